// Round 1
// baseline (2156.595 us; speedup 1.0000x reference)
//
#include <hip/hip_runtime.h>

#define TENC 64
#define TDEC 18
#define NDEC 24
#define NF1  17
#define NF2  129
#define HH   128
#define G4   512

// ---- d_ws float offsets: transposed weights ----
#define OFF_WIH1T 0        // [17][512]
#define OFF_WHH1T 8704     // [128][512]
#define OFF_WIH2T 74240    // [129][512]
#define OFF_WHH2T 140288   // [128][512]
#define OFF_WIHDT 205824   // [128][512]
#define OFF_WHHDT 271360   // [128][512]
#define OFF_WET   336896   // [256][64]
#define OFF_WE2T  353280   // [256][64]
#define OFF_WHT   369664   // [256][128]
#define OFF_WXT   402432   // [128][128]
#define OFF_WIT   418816   // [64][64]
#define OFF_WI2T  422912   // [64][64]

__device__ __forceinline__ float fsig(float x) { return 1.f / (1.f + __expf(-x)); }
__device__ __forceinline__ float ftanh(float x)
{
    x = fminf(fmaxf(x, -15.f), 15.f);
    float e = __expf(2.f * x);
    return (e - 1.f) / (e + 1.f);
}

// Transpose all 12 weight matrices into ws (row-major (R,C) -> (C,R)).
__global__ void transpose_all(
    const float* s0, const float* s1, const float* s2, const float* s3,
    const float* s4, const float* s5, const float* s6, const float* s7,
    const float* s8, const float* s9, const float* s10, const float* s11,
    float* ws)
{
    const int m = blockIdx.y;
    const float* src; int R, C, off;
    switch (m) {
        case 0:  src = s0;  R = 512; C = 17;  off = OFF_WIH1T; break;
        case 1:  src = s1;  R = 512; C = 128; off = OFF_WHH1T; break;
        case 2:  src = s2;  R = 512; C = 129; off = OFF_WIH2T; break;
        case 3:  src = s3;  R = 512; C = 128; off = OFF_WHH2T; break;
        case 4:  src = s4;  R = 512; C = 128; off = OFF_WIHDT; break;
        case 5:  src = s5;  R = 512; C = 128; off = OFF_WHHDT; break;
        case 6:  src = s6;  R = 64;  C = 256; off = OFF_WET;   break;
        case 7:  src = s7;  R = 64;  C = 256; off = OFF_WE2T;  break;
        case 8:  src = s8;  R = 128; C = 256; off = OFF_WHT;   break;
        case 9:  src = s9;  R = 128; C = 128; off = OFF_WXT;   break;
        case 10: src = s10; R = 64;  C = 64;  off = OFF_WIT;   break;
        default: src = s11; R = 64;  C = 64;  off = OFF_WI2T;  break;
    }
    int n = R * C;
    for (int i = blockIdx.x * blockDim.x + threadIdx.x; i < n; i += gridDim.x * blockDim.x)
        ws[off + (i % C) * R + (i / C)] = src[i];
}

// One WG = 2 batch elements through all 3 scans. 512 threads (8 waves), 1 WG/CU.
__global__ __launch_bounds__(512)
void dstp_main(const float* __restrict__ inq, const float* __restrict__ labp,
               const float* __restrict__ bih1, const float* __restrict__ bhh1,
               const float* __restrict__ bih2, const float* __restrict__ bhh2,
               const float* __restrict__ bihd, const float* __restrict__ bhhd,
               const float* __restrict__ Wi_b, const float* __restrict__ Vd_w, const float* __restrict__ Vd_b,
               const float* __restrict__ Wi2_b, const float* __restrict__ Vd2_w, const float* __restrict__ Vd2_b,
               const float* __restrict__ Wx_b, const float* __restrict__ V_w, const float* __restrict__ V_b,
               const float* __restrict__ reg_w, const float* __restrict__ reg_b,
               const float* __restrict__ ws, float* __restrict__ out)
{
    __shared__ float buf[2][TENC][HH];   // mid (phase B) then final (phase D) per b
    __shared__ float big[2][8385];       // WiX(17x65)+xin(64x17) / Wi2X(129x65) / WxF(64x129)
    __shared__ float hc[2][256];         // h[0:128], c[128:256]
    __shared__ float ebuf[2][128];
    __shared__ float sc[2][NF2];
    __shared__ float att[2][NF2];
    __shared__ float xav[2][NF2];
    __shared__ float pre[2][G4];
    __shared__ float lab[2][TENC];
    __shared__ float dinv[2][HH];
    __shared__ float vw1[64], vw2[64], vwf[128], rw[128];
    __shared__ float rsm[8];

    const int tid = threadIdx.x;
    const int b0  = blockIdx.x * 2;

    const float* WihT1 = ws + OFF_WIH1T;
    const float* WhhT1 = ws + OFF_WHH1T;
    const float* WihT2 = ws + OFF_WIH2T;
    const float* WhhT2 = ws + OFF_WHH2T;
    const float* WihTd = ws + OFF_WIHDT;
    const float* WhhTd = ws + OFF_WHHDT;
    const float* WeT   = ws + OFF_WET;
    const float* We2T  = ws + OFF_WE2T;
    const float* WhT   = ws + OFF_WHT;
    const float* WxT   = ws + OFF_WXT;
    const float* WiT   = ws + OFF_WIT;
    const float* Wi2T  = ws + OFF_WI2T;

    // per-thread (gate g = tid) bias sums
    const float bg1 = bih1[tid] + bhh1[tid];
    const float bg2 = bih2[tid] + bhh2[tid];
    const float bgd = bihd[tid] + bhhd[tid];

    // ================= Phase A: load inputs, WiX precompute =================
    hc[tid >> 8][tid & 255] = 0.f;
    if (tid < 2 * TENC) lab[tid >> 6][tid & 63] = labp[(b0 + (tid >> 6)) * TENC + (tid & 63)];
    if (tid < 64)        vw1[tid]       = Vd_w[tid];
    else if (tid < 128)  vw2[tid - 64]  = Vd2_w[tid - 64];
    else if (tid < 256)  vwf[tid - 128] = V_w[tid - 128];
    else if (tid < 384)  rw[tid - 256]  = reg_w[tid - 256];
    for (int i = tid; i < 2 * 1088; i += 512) {      // xin: x[t][f], f over COLS (skip col 14)
        int bb = i / 1088, r = i - bb * 1088, t = r / NF1, f = r - t * NF1;
        int col = f + (f >= 14);
        big[bb][1105 + r] = inq[((b0 + bb) * TENC + t) * 18 + col];
    }
    __syncthreads();
    for (int i = tid; i < 2 * NF1 * 64; i += 512) {  // WiX[f][j] = sum_t x[t][f]*Wi_w[j][t] + Wi_b[j]
        int bb = i / 1088, r = i - bb * 1088, f = r >> 6, j = r & 63;
        float acc = Wi_b[j];
        for (int t = 0; t < TENC; ++t)
            acc += big[bb][1105 + t * NF1 + f] * WiT[t * 64 + j];
        big[bb][f * 65 + j] = acc;                   // disjoint from xin region
    }
    __syncthreads();

    // ================= Phase B: encoder scan 1 (64 steps) =================
    for (int t = 0; t < TENC; ++t) {
        {   // e[j] = [h,c] @ We_w.T   (64 outs, 4-lane split over k)
            int bb = tid >> 8, j = (tid >> 2) & 63, p = tid & 3;
            float acc = 0.f;
            for (int kk = 0; kk < 64; ++kk) {
                int k = (kk << 2) | p;
                acc += hc[bb][k] * WeT[k * 64 + j];
            }
            acc += __shfl_xor(acc, 1, 4);
            acc += __shfl_xor(acc, 2, 4);
            if (p == 0) ebuf[bb][j] = acc;
        }
        __syncthreads();
        for (int i = tid; i < 2 * NF1 * 4; i += 512) {   // score[f] = tanh(WiX+e) @ Vd_w + Vd_b
            int bb = i / (NF1 * 4), r = i - bb * (NF1 * 4);
            int f = r >> 2, p = i & 3, j0 = p << 4;
            float acc = 0.f;
            for (int q = 0; q < 16; ++q) {
                int j = j0 + q;
                acc += ftanh(big[bb][f * 65 + j] + ebuf[bb][j]) * vw1[j];
            }
            acc += __shfl_xor(acc, 1, 4);
            acc += __shfl_xor(acc, 2, 4);
            if (p == 0) sc[bb][f] = acc + Vd_b[0];
        }
        __syncthreads();
        if (tid < 128) {   // softmax over 17
            int bb = tid >> 6, lane = tid & 63;
            float m = -1e30f;
            for (int f = lane; f < NF1; f += 64) m = fmaxf(m, sc[bb][f]);
            for (int d = 32; d; d >>= 1) m = fmaxf(m, __shfl_xor(m, d, 64));
            float ssum = 0.f;
            for (int f = lane; f < NF1; f += 64) { float e = __expf(sc[bb][f] - m); att[bb][f] = e; ssum += e; }
            for (int d = 32; d; d >>= 1) ssum += __shfl_xor(ssum, d, 64);
            float inv = 1.f / ssum;
            for (int f = lane; f < NF1; f += 64) att[bb][f] *= inv;
        }
        __syncthreads();
        if (tid < 2 * NF1) {
            int bb = tid / NF1, f = tid - bb * NF1;
            xav[bb][f] = big[bb][1105 + t * NF1 + f] * att[bb][f];
        }
        __syncthreads();
        {   // gates: g = tid, both batch elements share the weight stream
            float a0 = bg1, a1 = bg1;
            for (int f = 0; f < NF1; ++f) {
                float w = WihT1[f * G4 + tid];
                a0 += xav[0][f] * w;  a1 += xav[1][f] * w;
            }
            for (int k = 0; k < HH; ++k) {
                float w = WhhT1[k * G4 + tid];
                a0 += hc[0][k] * w;   a1 += hc[1][k] * w;
            }
            pre[0][tid] = a0; pre[1][tid] = a1;
        }
        __syncthreads();
        if (tid < 256) {   // LSTM pointwise
            int bb = tid >> 7, k = tid & 127;
            float gi = pre[bb][k], gf = pre[bb][HH + k], gg = pre[bb][2 * HH + k], go = pre[bb][3 * HH + k];
            float c2 = fsig(gf) * hc[bb][128 + k] + fsig(gi) * ftanh(gg);
            float h2 = fsig(go) * ftanh(c2);
            hc[bb][k] = h2; hc[bb][128 + k] = c2;
            buf[bb][t][k] = h2;                       // mid
        }
        __syncthreads();
    }

    // ================= Phase C: Wi2X precompute, reset state =================
    hc[tid >> 8][tid & 255] = 0.f;
    for (int i = tid; i < 2 * NF2 * 64; i += 512) {  // Wi2X[f][j] = sum_t mid2[t][f]*Wi2_w[j][t] + b
        int bb = i / 8256, r = i - bb * 8256, f = r >> 6, j = r & 63;
        float acc = Wi2_b[j];
        for (int tt = 0; tt < TENC; ++tt) {
            float m = (f < HH) ? buf[bb][tt][f] : lab[bb][tt];
            acc += m * Wi2T[tt * 64 + j];
        }
        big[bb][f * 65 + j] = acc;
    }
    __syncthreads();

    // ================= Phase D: encoder scan 2 (64 steps) =================
    for (int t = 0; t < TENC; ++t) {
        {
            int bb = tid >> 8, j = (tid >> 2) & 63, p = tid & 3;
            float acc = 0.f;
            for (int kk = 0; kk < 64; ++kk) {
                int k = (kk << 2) | p;
                acc += hc[bb][k] * We2T[k * 64 + j];
            }
            acc += __shfl_xor(acc, 1, 4);
            acc += __shfl_xor(acc, 2, 4);
            if (p == 0) ebuf[bb][j] = acc;
        }
        __syncthreads();
        for (int i = tid; i < 2 * NF2 * 4; i += 512) {
            int bb = i / (NF2 * 4), r = i - bb * (NF2 * 4);
            int f = r >> 2, p = i & 3, j0 = p << 4;
            float acc = 0.f;
            for (int q = 0; q < 16; ++q) {
                int j = j0 + q;
                acc += ftanh(big[bb][f * 65 + j] + ebuf[bb][j]) * vw2[j];
            }
            acc += __shfl_xor(acc, 1, 4);
            acc += __shfl_xor(acc, 2, 4);
            if (p == 0) sc[bb][f] = acc + Vd2_b[0];
        }
        __syncthreads();
        if (tid < 128) {   // softmax over 129
            int bb = tid >> 6, lane = tid & 63;
            float m = -1e30f;
            for (int f = lane; f < NF2; f += 64) m = fmaxf(m, sc[bb][f]);
            for (int d = 32; d; d >>= 1) m = fmaxf(m, __shfl_xor(m, d, 64));
            float ssum = 0.f;
            for (int f = lane; f < NF2; f += 64) { float e = __expf(sc[bb][f] - m); att[bb][f] = e; ssum += e; }
            for (int d = 32; d; d >>= 1) ssum += __shfl_xor(ssum, d, 64);
            float inv = 1.f / ssum;
            for (int f = lane; f < NF2; f += 64) att[bb][f] *= inv;
        }
        __syncthreads();
        if (tid < 2 * NF2) {
            int bb = tid / NF2, f = tid - bb * NF2;
            float x = (f < HH) ? buf[bb][t][f] : lab[bb][t];
            xav[bb][f] = x * att[bb][f];
        }
        __syncthreads();
        {
            float a0 = bg2, a1 = bg2;
            for (int f = 0; f < NF2; ++f) {
                float w = WihT2[f * G4 + tid];
                a0 += xav[0][f] * w;  a1 += xav[1][f] * w;
            }
            for (int k = 0; k < HH; ++k) {
                float w = WhhT2[k * G4 + tid];
                a0 += hc[0][k] * w;   a1 += hc[1][k] * w;
            }
            pre[0][tid] = a0; pre[1][tid] = a1;
        }
        __syncthreads();
        if (tid < 256) {
            int bb = tid >> 7, k = tid & 127;
            float gi = pre[bb][k], gf = pre[bb][HH + k], gg = pre[bb][2 * HH + k], go = pre[bb][3 * HH + k];
            float c2 = fsig(gf) * hc[bb][128 + k] + fsig(gi) * ftanh(gg);
            float h2 = fsig(go) * ftanh(c2);
            hc[bb][k] = h2; hc[bb][128 + k] = c2;
            buf[bb][t][k] = h2;                       // final overwrites mid row t (already consumed)
        }
        __syncthreads();
    }

    // ================= Phase E: WxF precompute, reset state =================
    hc[tid >> 8][tid & 255] = 0.f;
    for (int i = tid; i < 2 * TENC * HH; i += 512) { // WxF[t][j] = final[t] @ Wx_w.T + Wx_b
        int bb = i >> 13, r = i & 8191, tt = r >> 7, j = r & 127;
        float acc = Wx_b[j];
        for (int k = 0; k < HH; ++k)
            acc += buf[bb][tt][k] * WxT[k * HH + j];
        big[bb][tt * 129 + j] = acc;
    }
    __syncthreads();

    // ================= Phase F: decoder (24 steps) =================
    for (int n = 0; n < NDEC; ++n) {
        {   // e[j] = [h,c] @ Wh_w.T   (128 outs, 2-lane split)
            int bb = tid >> 8, j = (tid >> 1) & 127, p = tid & 1;
            float acc = 0.f;
            for (int kk = 0; kk < 128; ++kk) {
                int k = (kk << 1) | p;
                acc += hc[bb][k] * WhT[k * HH + j];
            }
            acc += __shfl_xor(acc, 1, 2);
            if (p == 0) ebuf[bb][j] = acc;
        }
        __syncthreads();
        for (int i = tid; i < 2 * TENC * 8; i += 512) {  // s[tt] = tanh(WxF+e) @ V_w + V_b
            int bb = i >> 9, r = i & 511, tt = r >> 3, p = i & 7, j0 = p << 4;
            float acc = 0.f;
            for (int q = 0; q < 16; ++q) {
                int j = j0 + q;
                acc += ftanh(big[bb][tt * 129 + j] + ebuf[bb][j]) * vwf[j];
            }
            acc += __shfl_xor(acc, 1, 8);
            acc += __shfl_xor(acc, 2, 8);
            acc += __shfl_xor(acc, 4, 8);
            if (p == 0) sc[bb][tt] = acc + V_b[0];
        }
        __syncthreads();
        if (tid < 128) {   // softmax over 64 (time)
            int bb = tid >> 6, lane = tid & 63;
            float m = sc[bb][lane];
            for (int d = 32; d; d >>= 1) m = fmaxf(m, __shfl_xor(m, d, 64));
            float e = __expf(sc[bb][lane] - m);
            float ssum = e;
            for (int d = 32; d; d >>= 1) ssum += __shfl_xor(ssum, d, 64);
            att[bb][lane] = e / ssum;
        }
        __syncthreads();
        {   // din[k] = sum_t a[t] * final[t][k]
            int bb = tid >> 8, k = (tid >> 1) & 127, p = tid & 1;
            float acc = 0.f;
            for (int u = 0; u < 32; ++u) {
                int tt = (u << 1) | p;
                acc += att[bb][tt] * buf[bb][tt][k];
            }
            acc += __shfl_xor(acc, 1, 2);
            if (p == 0) dinv[bb][k] = acc;
        }
        __syncthreads();
        {
            float a0 = bgd, a1 = bgd;
            for (int k = 0; k < HH; ++k) {
                float w = WihTd[k * G4 + tid];
                a0 += dinv[0][k] * w;  a1 += dinv[1][k] * w;
            }
            for (int k = 0; k < HH; ++k) {
                float w = WhhTd[k * G4 + tid];
                a0 += hc[0][k] * w;    a1 += hc[1][k] * w;
            }
            pre[0][tid] = a0; pre[1][tid] = a1;
        }
        __syncthreads();
        if (tid < 256) {
            int bb = tid >> 7, k = tid & 127;
            float gi = pre[bb][k], gf = pre[bb][HH + k], gg = pre[bb][2 * HH + k], go = pre[bb][3 * HH + k];
            float c2 = fsig(gf) * hc[bb][128 + k] + fsig(gi) * ftanh(gg);
            float h2 = fsig(go) * ftanh(c2);
            hc[bb][k] = h2; hc[bb][128 + k] = c2;
        }
        __syncthreads();
        if (n >= 6) {      // out[b][n-6] = h @ reg_w + reg_b
            if (tid < 256) {
                int bb = tid >> 7, k = tid & 127;
                float v = hc[bb][k] * rw[k];
                for (int d = 32; d; d >>= 1) v += __shfl_xor(v, d, 64);
                if ((tid & 63) == 0) rsm[tid >> 6] = v;
            }
            __syncthreads();
            if (tid < 2)
                out[(b0 + tid) * TDEC + (n - 6)] = rsm[tid * 2] + rsm[tid * 2 + 1] + reg_b[0];
            __syncthreads();
        }
    }
}

extern "C" void kernel_launch(void* const* d_in, const int* in_sizes, int n_in,
                              void* d_out, int out_size, void* d_ws, size_t ws_size,
                              hipStream_t stream)
{
    const float* inq   = (const float*)d_in[0];
    const float* labp  = (const float*)d_in[1];
    const float* Wih1  = (const float*)d_in[2];
    const float* Whh1  = (const float*)d_in[3];
    const float* bih1  = (const float*)d_in[4];
    const float* bhh1  = (const float*)d_in[5];
    const float* Wih2  = (const float*)d_in[6];
    const float* Whh2  = (const float*)d_in[7];
    const float* bih2  = (const float*)d_in[8];
    const float* bhh2  = (const float*)d_in[9];
    const float* Wihd  = (const float*)d_in[10];
    const float* Whhd  = (const float*)d_in[11];
    const float* bihd  = (const float*)d_in[12];
    const float* bhhd  = (const float*)d_in[13];
    const float* Wi_w  = (const float*)d_in[14];
    const float* Wi_b  = (const float*)d_in[15];
    const float* We_w  = (const float*)d_in[16];
    const float* Vd_w  = (const float*)d_in[17];
    const float* Vd_b  = (const float*)d_in[18];
    const float* Wi2_w = (const float*)d_in[19];
    const float* Wi2_b = (const float*)d_in[20];
    const float* We2_w = (const float*)d_in[21];
    const float* Vd2_w = (const float*)d_in[22];
    const float* Vd2_b = (const float*)d_in[23];
    const float* Wx_w  = (const float*)d_in[24];
    const float* Wx_b  = (const float*)d_in[25];
    const float* Wh_w  = (const float*)d_in[26];
    const float* V_w   = (const float*)d_in[27];
    const float* V_b   = (const float*)d_in[28];
    const float* reg_w = (const float*)d_in[29];
    const float* reg_b = (const float*)d_in[30];
    float* ws  = (float*)d_ws;
    float* out = (float*)d_out;

    dim3 tg(64, 12);
    transpose_all<<<tg, 256, 0, stream>>>(Wih1, Whh1, Wih2, Whh2, Wihd, Whhd,
                                          We_w, We2_w, Wh_w, Wx_w, Wi_w, Wi2_w, ws);
    dstp_main<<<256, 512, 0, stream>>>(inq, labp, bih1, bhh1, bih2, bhh2, bihd, bhhd,
                                       Wi_b, Vd_w, Vd_b, Wi2_b, Vd2_w, Vd2_b,
                                       Wx_b, V_w, V_b, reg_w, reg_b, ws, out);
}

// Round 2
// 1578.744 us; speedup vs baseline: 1.3660x; 1.3660x over previous
//
#include <hip/hip_runtime.h>

#define TENC 64
#define TDEC 18
#define NDEC 24
#define NF1  17
#define NF2  129
#define HH   128

// ---- packed weight offsets in d_ws (float units) ----
// layout: Wp[kk][g] as float4 = { W[g][4kk+0..3] }, zero-padded to Kp
#define OFF_WIH1 0        // 512 x Kp20  -> 10240
#define OFF_WHH1 10240    // 512 x 128   -> 65536
#define OFF_WIH2 75776    // 512 x Kp132 -> 67584
#define OFF_WHH2 143360   // 512 x 128   -> 65536
#define OFF_WIHD 208896   // 512 x 128
#define OFF_WHHD 274432   // 512 x 128
#define OFF_WE   339968   // 64  x 256   -> 16384
#define OFF_WE2  356352   // 64  x 256
#define OFF_WH   372736   // 128 x 256   -> 32768
#define OFF_WX   405504   // 128 x 128   -> 16384
#define OFF_WI   421888   // 64  x 64    -> 4096
#define OFF_WI2  425984   // 64  x 64    -> 4096

#define SB   68     // WiX / Wi2X row stride (floats), 16B-aligned, 68%32=4 spreads banks
#define SWF  132    // WxF row stride
#define XIN  1200   // xin region offset inside big[bb]
#define BIGN 8772   // per-b big size (129*68)

__device__ __forceinline__ float fsig(float x) { return 1.f / (1.f + __expf(-x)); }
__device__ __forceinline__ float ftanh(float x)
{
    x = fminf(fmaxf(x, -15.f), 15.f);
    float e = __expf(2.f * x);
    return (e - 1.f) / (e + 1.f);
}
__device__ __forceinline__ float dot4(float4 a, float4 b)
{ return a.x * b.x + a.y * b.y + a.z * b.z + a.w * b.w; }

// Pack W[G][K] row-major -> Wp[K/4][G] float4 (k zero-padded to Kp).
__global__ void pack_all(
    const float* s0, const float* s1, const float* s2, const float* s3,
    const float* s4, const float* s5, const float* s6, const float* s7,
    const float* s8, const float* s9, const float* s10, const float* s11,
    float* ws)
{
    const int m = blockIdx.y;
    const float* src; int G, K, Kp, off;
    switch (m) {
        case 0:  src = s0;  G = 512; K = 17;  Kp = 20;  off = OFF_WIH1; break;
        case 1:  src = s1;  G = 512; K = 128; Kp = 128; off = OFF_WHH1; break;
        case 2:  src = s2;  G = 512; K = 129; Kp = 132; off = OFF_WIH2; break;
        case 3:  src = s3;  G = 512; K = 128; Kp = 128; off = OFF_WHH2; break;
        case 4:  src = s4;  G = 512; K = 128; Kp = 128; off = OFF_WIHD; break;
        case 5:  src = s5;  G = 512; K = 128; Kp = 128; off = OFF_WHHD; break;
        case 6:  src = s6;  G = 64;  K = 256; Kp = 256; off = OFF_WE;   break;
        case 7:  src = s7;  G = 64;  K = 256; Kp = 256; off = OFF_WE2;  break;
        case 8:  src = s8;  G = 128; K = 256; Kp = 256; off = OFF_WH;   break;
        case 9:  src = s9;  G = 128; K = 128; Kp = 128; off = OFF_WX;   break;
        case 10: src = s10; G = 64;  K = 64;  Kp = 64;  off = OFF_WI;   break;
        default: src = s11; G = 64;  K = 64;  Kp = 64;  off = OFF_WI2;  break;
    }
    const int n = G * Kp;
    for (int i = blockIdx.x * blockDim.x + threadIdx.x; i < n; i += gridDim.x * blockDim.x) {
        int q = i & 3, gk = i >> 2;
        int kk = gk / G, g = gk - kk * G;
        int k = kk * 4 + q;
        ws[off + i] = (k < K) ? src[g * K + k] : 0.f;
    }
}

// One WG = 1024 threads (16 waves), 2 batch elements, all 152 recurrent steps.
__global__ __launch_bounds__(1024)
void dstp_main(const float* __restrict__ inq, const float* __restrict__ labp,
               const float* __restrict__ bih1, const float* __restrict__ bhh1,
               const float* __restrict__ bih2, const float* __restrict__ bhh2,
               const float* __restrict__ bihd, const float* __restrict__ bhhd,
               const float* __restrict__ Wi_b, const float* __restrict__ Vd_b,
               const float* __restrict__ Vd_w, const float* __restrict__ Vd2_w,
               const float* __restrict__ Wi2_b, const float* __restrict__ Vd2_b,
               const float* __restrict__ Wx_b, const float* __restrict__ V_w, const float* __restrict__ V_b,
               const float* __restrict__ reg_w, const float* __restrict__ reg_b,
               const float* __restrict__ ws, float* __restrict__ out)
{
    __shared__ __align__(16) float buf[2][TENC][HH];    // mid then final
    __shared__ __align__(16) float big[2][BIGN];        // WiX+xin / Wi2X / WxF
    __shared__ __align__(16) float hc[2][256];          // h[0:128], c[128:256]
    __shared__ __align__(16) float ebuf[2][128];
    __shared__ float sc[2][NF2];
    __shared__ float att[2][NF2];
    __shared__ __align__(16) float xav[2][136];         // padded: B->20, D->132
    __shared__ float pre2[2][2][512];                   // [khalf][bb][gate]
    __shared__ float lab[2][TENC];
    __shared__ __align__(16) float dinv[2][HH];
    __shared__ __align__(16) float vw1[64], vw2[64], vwf[128], rw[128];
    __shared__ float rsm[4];

    const int tid = threadIdx.x;
    const int b0  = blockIdx.x * 2;
    const int p   = tid >> 9;     // k-half (wave-uniform)
    const int g   = tid & 511;    // gate index

    const float4* Wih1p = (const float4*)(ws + OFF_WIH1);
    const float4* Whh1p = (const float4*)(ws + OFF_WHH1);
    const float4* Wih2p = (const float4*)(ws + OFF_WIH2);
    const float4* Whh2p = (const float4*)(ws + OFF_WHH2);
    const float4* Wihdp = (const float4*)(ws + OFF_WIHD);
    const float4* Whhdp = (const float4*)(ws + OFF_WHHD);
    const float4* Wep   = (const float4*)(ws + OFF_WE);
    const float4* We2p  = (const float4*)(ws + OFF_WE2);
    const float4* Whp   = (const float4*)(ws + OFF_WH);
    const float4* Wxp   = (const float4*)(ws + OFF_WX);
    const float4* Wip   = (const float4*)(ws + OFF_WI);
    const float4* Wi2p  = (const float4*)(ws + OFF_WI2);

    const float bg1 = bih1[g] + bhh1[g];
    const float bg2 = bih2[g] + bhh2[g];
    const float bgd = bihd[g] + bhhd[g];

    // ================= Phase A: init, inputs, WiX =================
    if (tid < 512) hc[tid >> 8][tid & 255] = 0.f;
    if (tid < 2 * TENC) lab[tid >> 6][tid & 63] = labp[(b0 + (tid >> 6)) * TENC + (tid & 63)];
    if (tid < 272) xav[tid / 136][tid % 136] = 0.f;
    {
        int v = tid - 272;
        if (v >= 0 && v < 64)        vw1[v]       = Vd_w[v];
        else if (v >= 64 && v < 128) vw2[v - 64]  = Vd2_w[v - 64];
        else if (v >= 128 && v < 256) vwf[v - 128] = V_w[v - 128];
        else if (v >= 256 && v < 384) rw[v - 256]  = reg_w[v - 256];
    }
    for (int i = tid; i < 2176; i += 1024) {             // xin: x[t][f], COLS skip 14
        int bb = i / 1088, r = i - bb * 1088, t = r / NF1, f = r - t * NF1;
        big[bb][XIN + r] = inq[((b0 + bb) * TENC + t) * 18 + f + (f >= 14)];
    }
    __syncthreads();
    for (int i = tid; i < 2176; i += 1024) {             // WiX[f][j]
        int bb = i / 1088, r = i - bb * 1088, f = r >> 6, j = r & 63;
        float acc = Wi_b[j];
        for (int tt = 0; tt < 16; ++tt) {
            float4 w = Wip[tt * 64 + j];
            acc += big[bb][XIN + (4 * tt + 0) * NF1 + f] * w.x
                 + big[bb][XIN + (4 * tt + 1) * NF1 + f] * w.y
                 + big[bb][XIN + (4 * tt + 2) * NF1 + f] * w.z
                 + big[bb][XIN + (4 * tt + 3) * NF1 + f] * w.w;
        }
        big[bb][f * SB + j] = acc;
    }
    __syncthreads();

    // ================= Phase B: encoder scan 1 =================
    for (int t = 0; t < TENC; ++t) {
        {   // e[j] = [h,c] @ We.T : (bb, j, pp in 0..7), 8 f4 each
            int bb = tid >> 9, r = tid & 511, j = r >> 3, pp = r & 7;
            const float4* hv = (const float4*)hc[bb];
            float acc = 0.f;
            #pragma unroll
            for (int kk = 0; kk < 8; ++kk) {
                int k4 = pp * 8 + kk;
                acc += dot4(Wep[k4 * 64 + j], hv[k4]);
            }
            acc += __shfl_xor(acc, 1, 8);
            acc += __shfl_xor(acc, 2, 8);
            acc += __shfl_xor(acc, 4, 8);
            if (pp == 0) ebuf[bb][j] = acc;
        }
        __syncthreads();
        if (tid < 544) {   // score[f]: 16 threads per (bb,f)
            int bb = tid / 272, r = tid - bb * 272, f = r >> 4, pp = r & 15;
            float4 wx = *(const float4*)&big[bb][f * SB + pp * 4];
            float4 e4 = *(const float4*)&ebuf[bb][pp * 4];
            float4 v4 = *(const float4*)&vw1[pp * 4];
            float acc = ftanh(wx.x + e4.x) * v4.x + ftanh(wx.y + e4.y) * v4.y
                      + ftanh(wx.z + e4.z) * v4.z + ftanh(wx.w + e4.w) * v4.w;
            acc += __shfl_xor(acc, 1, 16);
            acc += __shfl_xor(acc, 2, 16);
            acc += __shfl_xor(acc, 4, 16);
            acc += __shfl_xor(acc, 8, 16);
            if (pp == 0) sc[bb][f] = acc + Vd_b[0];
        }
        __syncthreads();
        if (tid < 128) {   // softmax(17) + xav fused
            int bb = tid >> 6, lane = tid & 63;
            float v = (lane < NF1) ? sc[bb][lane] : -1e30f;
            float m = v;
            for (int d = 32; d; d >>= 1) m = fmaxf(m, __shfl_xor(m, d, 64));
            float e = (lane < NF1) ? __expf(v - m) : 0.f;
            float s = e;
            for (int d = 32; d; d >>= 1) s += __shfl_xor(s, d, 64);
            if (lane < NF1) xav[bb][lane] = big[bb][XIN + t * NF1 + lane] * (e / s);
        }
        __syncthreads();
        {   // gates, k-split across p
            float a0, a1;
            if (p == 0) {
                a0 = bg1; a1 = bg1;
                const float4* x0 = (const float4*)xav[0];
                const float4* x1 = (const float4*)xav[1];
                #pragma unroll
                for (int kk = 0; kk < 5; ++kk) {
                    float4 w = Wih1p[kk * 512 + g];
                    a0 += dot4(w, x0[kk]); a1 += dot4(w, x1[kk]);
                }
                const float4* h0 = (const float4*)hc[0];
                const float4* h1 = (const float4*)hc[1];
                #pragma unroll 7
                for (int kk = 0; kk < 14; ++kk) {
                    float4 w = Whh1p[kk * 512 + g];
                    a0 += dot4(w, h0[kk]); a1 += dot4(w, h1[kk]);
                }
            } else {
                a0 = 0.f; a1 = 0.f;
                const float4* h0 = (const float4*)hc[0];
                const float4* h1 = (const float4*)hc[1];
                #pragma unroll 6
                for (int kk = 14; kk < 32; ++kk) {
                    float4 w = Whh1p[kk * 512 + g];
                    a0 += dot4(w, h0[kk]); a1 += dot4(w, h1[kk]);
                }
            }
            pre2[p][0][g] = a0; pre2[p][1][g] = a1;
        }
        __syncthreads();
        if (tid < 256) {   // LSTM pointwise
            int bb = tid >> 7, k = tid & 127;
            float gi = pre2[0][bb][k]        + pre2[1][bb][k];
            float gf = pre2[0][bb][128 + k]  + pre2[1][bb][128 + k];
            float gg = pre2[0][bb][256 + k]  + pre2[1][bb][256 + k];
            float go = pre2[0][bb][384 + k]  + pre2[1][bb][384 + k];
            float c2 = fsig(gf) * hc[bb][128 + k] + fsig(gi) * ftanh(gg);
            float h2 = fsig(go) * ftanh(c2);
            hc[bb][k] = h2; hc[bb][128 + k] = c2;
            buf[bb][t][k] = h2;
        }
        __syncthreads();
    }

    // ================= Phase C: Wi2X, reset state =================
    if (tid < 512) hc[tid >> 8][tid & 255] = 0.f;
    for (int i = tid; i < 16512; i += 1024) {
        int bb = i / 8256, r = i - bb * 8256, f = r >> 6, j = r & 63;
        float acc = Wi2_b[j];
        for (int tt = 0; tt < 16; ++tt) {
            float4 w = Wi2p[tt * 64 + j];
            float m0, m1, m2, m3;
            if (f < HH) {
                m0 = buf[bb][4 * tt][f];     m1 = buf[bb][4 * tt + 1][f];
                m2 = buf[bb][4 * tt + 2][f]; m3 = buf[bb][4 * tt + 3][f];
            } else {
                m0 = lab[bb][4 * tt];     m1 = lab[bb][4 * tt + 1];
                m2 = lab[bb][4 * tt + 2]; m3 = lab[bb][4 * tt + 3];
            }
            acc += m0 * w.x + m1 * w.y + m2 * w.z + m3 * w.w;
        }
        big[bb][f * SB + j] = acc;
    }
    __syncthreads();

    // ================= Phase D: encoder scan 2 =================
    for (int t = 0; t < TENC; ++t) {
        {   // e[j] = [h,c] @ We2.T
            int bb = tid >> 9, r = tid & 511, j = r >> 3, pp = r & 7;
            const float4* hv = (const float4*)hc[bb];
            float acc = 0.f;
            #pragma unroll
            for (int kk = 0; kk < 8; ++kk) {
                int k4 = pp * 8 + kk;
                acc += dot4(We2p[k4 * 64 + j], hv[k4]);
            }
            acc += __shfl_xor(acc, 1, 8);
            acc += __shfl_xor(acc, 2, 8);
            acc += __shfl_xor(acc, 4, 8);
            if (pp == 0) ebuf[bb][j] = acc;
        }
        __syncthreads();
        for (int i = tid; i < 1032; i += 1024) {   // score[f]: 4 threads per (bb,f)
            int bb = i / 516, r = i - bb * 516, f = r >> 2, pp = r & 3;
            float acc = 0.f;
            #pragma unroll
            for (int c = 0; c < 4; ++c) {
                float4 wx = *(const float4*)&big[bb][f * SB + pp * 16 + c * 4];
                float4 e4 = *(const float4*)&ebuf[bb][pp * 16 + c * 4];
                float4 v4 = *(const float4*)&vw2[pp * 16 + c * 4];
                acc += ftanh(wx.x + e4.x) * v4.x + ftanh(wx.y + e4.y) * v4.y
                     + ftanh(wx.z + e4.z) * v4.z + ftanh(wx.w + e4.w) * v4.w;
            }
            acc += __shfl_xor(acc, 1, 4);
            acc += __shfl_xor(acc, 2, 4);
            if (pp == 0) sc[bb][f] = acc + Vd2_b[0];
        }
        __syncthreads();
        if (tid < 128) {   // softmax(129) + xav fused
            int bb = tid >> 6, lane = tid & 63;
            float m = -1e30f;
            for (int f = lane; f < NF2; f += 64) m = fmaxf(m, sc[bb][f]);
            for (int d = 32; d; d >>= 1) m = fmaxf(m, __shfl_xor(m, d, 64));
            float s = 0.f;
            float ev[3]; int nf = 0;
            for (int f = lane; f < NF2; f += 64) { ev[nf] = __expf(sc[bb][f] - m); s += ev[nf]; ++nf; }
            for (int d = 32; d; d >>= 1) s += __shfl_xor(s, d, 64);
            float inv = 1.f / s;
            nf = 0;
            for (int f = lane; f < NF2; f += 64) {
                float x = (f < HH) ? buf[bb][t][f] : lab[bb][t];
                xav[bb][f] = x * ev[nf++] * inv;
            }
        }
        __syncthreads();
        {   // gates
            float a0, a1;
            if (p == 0) {
                a0 = bg2; a1 = bg2;
                const float4* x0 = (const float4*)xav[0];
                const float4* x1 = (const float4*)xav[1];
                #pragma unroll 11
                for (int kk = 0; kk < 33; ++kk) {
                    float4 w = Wih2p[kk * 512 + g];
                    a0 += dot4(w, x0[kk]); a1 += dot4(w, x1[kk]);
                }
            } else {
                a0 = 0.f; a1 = 0.f;
                const float4* h0 = (const float4*)hc[0];
                const float4* h1 = (const float4*)hc[1];
                #pragma unroll 8
                for (int kk = 0; kk < 32; ++kk) {
                    float4 w = Whh2p[kk * 512 + g];
                    a0 += dot4(w, h0[kk]); a1 += dot4(w, h1[kk]);
                }
            }
            pre2[p][0][g] = a0; pre2[p][1][g] = a1;
        }
        __syncthreads();
        if (tid < 256) {
            int bb = tid >> 7, k = tid & 127;
            float gi = pre2[0][bb][k]        + pre2[1][bb][k];
            float gf = pre2[0][bb][128 + k]  + pre2[1][bb][128 + k];
            float gg = pre2[0][bb][256 + k]  + pre2[1][bb][256 + k];
            float go = pre2[0][bb][384 + k]  + pre2[1][bb][384 + k];
            float c2 = fsig(gf) * hc[bb][128 + k] + fsig(gi) * ftanh(gg);
            float h2 = fsig(go) * ftanh(c2);
            hc[bb][k] = h2; hc[bb][128 + k] = c2;
            buf[bb][t][k] = h2;               // final overwrites consumed mid row
        }
        __syncthreads();
    }

    // ================= Phase E: WxF, reset state =================
    if (tid < 512) hc[tid >> 8][tid & 255] = 0.f;
    for (int i = tid; i < 16384; i += 1024) {
        int bb = i >> 13, r = i & 8191, tt = r >> 7, j = r & 127;
        float acc = Wx_b[j];
        const float4* bv = (const float4*)buf[bb][tt];
        #pragma unroll 8
        for (int kk = 0; kk < 32; ++kk)
            acc += dot4(Wxp[kk * 128 + j], bv[kk]);
        big[bb][tt * SWF + j] = acc;
    }
    __syncthreads();

    // ================= Phase F: decoder =================
    for (int n = 0; n < NDEC; ++n) {
        {   // e[j] = [h,c] @ Wh.T : (bb, j in 0..127, pp in 0..3)
            int bb = tid >> 9, r = tid & 511, j = r >> 2, pp = r & 3;
            const float4* hv = (const float4*)hc[bb];
            float acc = 0.f;
            #pragma unroll
            for (int kk = 0; kk < 16; ++kk) {
                int k4 = pp * 16 + kk;
                acc += dot4(Whp[k4 * 128 + j], hv[k4]);
            }
            acc += __shfl_xor(acc, 1, 4);
            acc += __shfl_xor(acc, 2, 4);
            if (pp == 0) ebuf[bb][j] = acc;
        }
        __syncthreads();
        {   // s[tt]: 8 threads per (bb,tt)
            int bb = tid >> 9, r = tid & 511, tt = r >> 3, pp = r & 7;
            float acc = 0.f;
            #pragma unroll
            for (int c = 0; c < 4; ++c) {
                float4 wx = *(const float4*)&big[bb][tt * SWF + pp * 16 + c * 4];
                float4 e4 = *(const float4*)&ebuf[bb][pp * 16 + c * 4];
                float4 v4 = *(const float4*)&vwf[pp * 16 + c * 4];
                acc += ftanh(wx.x + e4.x) * v4.x + ftanh(wx.y + e4.y) * v4.y
                     + ftanh(wx.z + e4.z) * v4.z + ftanh(wx.w + e4.w) * v4.w;
            }
            acc += __shfl_xor(acc, 1, 8);
            acc += __shfl_xor(acc, 2, 8);
            acc += __shfl_xor(acc, 4, 8);
            if (pp == 0) sc[bb][tt] = acc + V_b[0];
        }
        __syncthreads();
        if (tid < 128) {   // softmax(64) over time
            int bb = tid >> 6, lane = tid & 63;
            float v = sc[bb][lane];
            float m = v;
            for (int d = 32; d; d >>= 1) m = fmaxf(m, __shfl_xor(m, d, 64));
            float e = __expf(v - m);
            float s = e;
            for (int d = 32; d; d >>= 1) s += __shfl_xor(s, d, 64);
            att[bb][lane] = e / s;
        }
        __syncthreads();
        {   // din[k] = sum_t a[t]*final[t][k]
            int bb = tid >> 9, r = tid & 511, k = r >> 2, pp = r & 3;
            float acc = 0.f;
            #pragma unroll
            for (int u = 0; u < 16; ++u) {
                int tt = u * 4 + pp;
                acc += att[bb][tt] * buf[bb][tt][k];
            }
            acc += __shfl_xor(acc, 1, 4);
            acc += __shfl_xor(acc, 2, 4);
            if (pp == 0) dinv[bb][k] = acc;
        }
        __syncthreads();
        {   // gates
            float a0, a1;
            if (p == 0) {
                a0 = bgd; a1 = bgd;
                const float4* x0 = (const float4*)dinv[0];
                const float4* x1 = (const float4*)dinv[1];
                #pragma unroll 8
                for (int kk = 0; kk < 32; ++kk) {
                    float4 w = Wihdp[kk * 512 + g];
                    a0 += dot4(w, x0[kk]); a1 += dot4(w, x1[kk]);
                }
            } else {
                a0 = 0.f; a1 = 0.f;
                const float4* h0 = (const float4*)hc[0];
                const float4* h1 = (const float4*)hc[1];
                #pragma unroll 8
                for (int kk = 0; kk < 32; ++kk) {
                    float4 w = Whhdp[kk * 512 + g];
                    a0 += dot4(w, h0[kk]); a1 += dot4(w, h1[kk]);
                }
            }
            pre2[p][0][g] = a0; pre2[p][1][g] = a1;
        }
        __syncthreads();
        if (tid < 256) {   // pointwise + fused output reduction
            int bb = tid >> 7, k = tid & 127;
            float gi = pre2[0][bb][k]        + pre2[1][bb][k];
            float gf = pre2[0][bb][128 + k]  + pre2[1][bb][128 + k];
            float gg = pre2[0][bb][256 + k]  + pre2[1][bb][256 + k];
            float go = pre2[0][bb][384 + k]  + pre2[1][bb][384 + k];
            float c2 = fsig(gf) * hc[bb][128 + k] + fsig(gi) * ftanh(gg);
            float h2 = fsig(go) * ftanh(c2);
            hc[bb][k] = h2; hc[bb][128 + k] = c2;
            if (n >= 6) {
                float v = h2 * rw[k];
                for (int d = 32; d; d >>= 1) v += __shfl_xor(v, d, 64);
                if ((tid & 63) == 0) rsm[tid >> 6] = v;
            }
        }
        __syncthreads();
        if (n >= 6 && tid < 2)
            out[(b0 + tid) * TDEC + (n - 6)] = rsm[tid * 2] + rsm[tid * 2 + 1] + reg_b[0];
    }
}

extern "C" void kernel_launch(void* const* d_in, const int* in_sizes, int n_in,
                              void* d_out, int out_size, void* d_ws, size_t ws_size,
                              hipStream_t stream)
{
    const float* inq   = (const float*)d_in[0];
    const float* labp  = (const float*)d_in[1];
    const float* Wih1  = (const float*)d_in[2];
    const float* Whh1  = (const float*)d_in[3];
    const float* bih1  = (const float*)d_in[4];
    const float* bhh1  = (const float*)d_in[5];
    const float* Wih2  = (const float*)d_in[6];
    const float* Whh2  = (const float*)d_in[7];
    const float* bih2  = (const float*)d_in[8];
    const float* bhh2  = (const float*)d_in[9];
    const float* Wihd  = (const float*)d_in[10];
    const float* Whhd  = (const float*)d_in[11];
    const float* bihd  = (const float*)d_in[12];
    const float* bhhd  = (const float*)d_in[13];
    const float* Wi_w  = (const float*)d_in[14];
    const float* Wi_b  = (const float*)d_in[15];
    const float* We_w  = (const float*)d_in[16];
    const float* Vd_w  = (const float*)d_in[17];
    const float* Vd_b  = (const float*)d_in[18];
    const float* Wi2_w = (const float*)d_in[19];
    const float* Wi2_b = (const float*)d_in[20];
    const float* We2_w = (const float*)d_in[21];
    const float* Vd2_w = (const float*)d_in[22];
    const float* Vd2_b = (const float*)d_in[23];
    const float* Wx_w  = (const float*)d_in[24];
    const float* Wx_b  = (const float*)d_in[25];
    const float* Wh_w  = (const float*)d_in[26];
    const float* V_w   = (const float*)d_in[27];
    const float* V_b   = (const float*)d_in[28];
    const float* reg_w = (const float*)d_in[29];
    const float* reg_b = (const float*)d_in[30];
    float* ws  = (float*)d_ws;
    float* out = (float*)d_out;

    pack_all<<<dim3(64, 12), 256, 0, stream>>>(Wih1, Whh1, Wih2, Whh2, Wihd, Whhd,
                                               We_w, We2_w, Wh_w, Wx_w, Wi_w, Wi2_w, ws);
    dstp_main<<<256, 1024, 0, stream>>>(inq, labp, bih1, bhh1, bih2, bhh2, bihd, bhhd,
                                        Wi_b, Vd_b, Vd_w, Vd2_w, Wi2_b, Vd2_b,
                                        Wx_b, V_w, V_b, reg_w, reg_b, ws, out);
}